// Round 1
// baseline (255.851 us; speedup 1.0000x reference)
//
#include <hip/hip_runtime.h>

#define DEVFN __device__ __forceinline__

typedef __attribute__((ext_vector_type(8))) short bf16x8;
typedef __attribute__((ext_vector_type(4))) float f32x4;

#define MFMA16(a, b, c) __builtin_amdgcn_mfma_f32_16x16x32_bf16(a, b, c, 0, 0, 0)

DEVFN unsigned short f2bf(float f) {
  union { float f; unsigned u; } v; v.f = f;
  unsigned r = v.u + 0x7FFFu + ((v.u >> 16) & 1u);
  return (unsigned short)(r >> 16);
}
DEVFN unsigned pack2bf(float a, float b) {
  return (unsigned)f2bf(a) | ((unsigned)f2bf(b) << 16);
}
DEVFN void gll16(const void* g, void* l) {
  __builtin_amdgcn_global_load_lds((__attribute__((address_space(1))) void*)g,
                                   (__attribute__((address_space(3))) void*)l,
                                   16, 0, 0);
}

// ---------------- precompute kernels ----------------

__global__ __launch_bounds__(256) void conv_x_k(const float* __restrict__ x,
                                                unsigned short* __restrict__ xb) {
  int i = (blockIdx.x * 256 + threadIdx.x) * 4;
  float4 v = *(const float4*)(x + i);
  uint2 u;
  u.x = pack2bf(v.x, v.y);
  u.y = pack2bf(v.z, v.w);
  *(uint2*)(xb + i) = u;
}

// WT[n][k] = (bf16) W[k][n], 64x64 tiles through LDS
__global__ __launch_bounds__(256) void transp_k(
    const float* __restrict__ Wq, const float* __restrict__ Wk,
    const float* __restrict__ Wv, const float* __restrict__ Wo,
    unsigned short* __restrict__ Tq, unsigned short* __restrict__ Tk,
    unsigned short* __restrict__ Tv, unsigned short* __restrict__ To) {
  __shared__ unsigned short t[64 * 65];
  int z = blockIdx.z;
  const float* src = (z == 0) ? Wq : (z == 1) ? Wk : (z == 2) ? Wv : Wo;
  unsigned short* dst = (z == 0) ? Tq : (z == 1) ? Tk : (z == 2) ? Tv : To;
  int k0 = blockIdx.x * 64, n0 = blockIdx.y * 64;
  int tid = threadIdx.x;
#pragma unroll
  for (int i = 0; i < 16; ++i) {
    int flat = i * 256 + tid;
    int r = flat >> 6, cc = flat & 63;
    t[cc * 65 + r] = f2bf(src[(size_t)(k0 + r) * 1024 + n0 + cc]);
  }
  __syncthreads();
#pragma unroll
  for (int i = 0; i < 16; ++i) {
    int flat = i * 256 + tid;
    int rr = flat >> 6, cc = flat & 63;
    dst[(size_t)(n0 + rr) * 1024 + k0 + cc] = t[rr * 65 + cc];
  }
}

__global__ __launch_bounds__(256) void rope_k(float* __restrict__ rsin,
                                              float* __restrict__ rcos) {
  int idx = blockIdx.x * 256 + threadIdx.x;  // 2048*32
  int s = idx >> 5, j = idx & 31;
  // div_term[j] = exp(-(2j) * ln(10000)/64) = exp(-j * ln(10000)/32)
  float freq = expf(-0.28782313714981824f * (float)j);
  float ang = (float)s * freq;
  rsin[idx] = sinf(ang);
  rcos[idx] = cosf(ang);
}

// ---------------- GEMM: C[8192,1024] = A(bf16) @ W, B given as WT[n][k] ----
// MODE 0: Q epilogue (RoPE + 0.125 scale) -> [BH][S][D] bf16
// MODE 1: K epilogue (RoPE)               -> [BH][S][D] bf16
// MODE 2: V epilogue (transposed)         -> [BH][D][S] bf16
// MODE 3: plain fp32                       -> d_out [8192][1024]
template <int MODE>
__global__ __launch_bounds__(256) void gemm_k(
    const unsigned short* __restrict__ A, const unsigned short* __restrict__ WT,
    void* __restrict__ outp, const float* __restrict__ rsin,
    const float* __restrict__ rcos) {
  __shared__ unsigned short At[128 * 64];
  __shared__ unsigned short Bt[128 * 64];
  const int tid = threadIdx.x;
  const int w = tid >> 6, lane = tid & 63, g = lane >> 4, c = lane & 15;
  const int wr = w >> 1, wc = w & 1;
  const int m0 = blockIdx.x * 128, n0 = blockIdx.y * 128;

  f32x4 zero = {0.f, 0.f, 0.f, 0.f};
  f32x4 acc[4][4];
#pragma unroll
  for (int i = 0; i < 4; ++i)
#pragma unroll
    for (int j = 0; j < 4; ++j) acc[i][j] = zero;

  for (int k0 = 0; k0 < 1024; k0 += 64) {
#pragma unroll
    for (int p = 0; p < 4; ++p) {
      int i = p * 256 + tid;
      int row = i >> 3, ls = i & 7;
      size_t off = ((size_t)(m0 + row) * 1024 + k0) * 2 + ((ls ^ (row & 7)) << 4);
      gll16((const char*)A + off, (char*)At + p * 4096 + w * 1024);
      size_t offb = ((size_t)(n0 + row) * 1024 + k0) * 2 + ((ls ^ (row & 7)) << 4);
      gll16((const char*)WT + offb, (char*)Bt + p * 4096 + w * 1024);
    }
    __syncthreads();
#pragma unroll
    for (int ks = 0; ks < 2; ++ks) {
      bf16x8 af[4], bfv[4];
#pragma unroll
      for (int am = 0; am < 4; ++am) {
        int row = wr * 64 + am * 16 + c;
        af[am] = *(const bf16x8*)(At + row * 64 + ((((ks << 2) | g) ^ (row & 7)) << 3));
      }
#pragma unroll
      for (int bn = 0; bn < 4; ++bn) {
        int row = wc * 64 + bn * 16 + c;
        bfv[bn] = *(const bf16x8*)(Bt + row * 64 + ((((ks << 2) | g) ^ (row & 7)) << 3));
      }
#pragma unroll
      for (int am = 0; am < 4; ++am)
#pragma unroll
        for (int bn = 0; bn < 4; ++bn)
          acc[am][bn] = MFMA16(af[am], bfv[bn], acc[am][bn]);
    }
    __syncthreads();
  }

  // epilogue: C[row][col], row = m0+wr*64+am*16+g*4+r, col = n0+wc*64+bn*16+c
  if (MODE == 0 || MODE == 1) {
    unsigned short* outb = (unsigned short*)outp;
#pragma unroll
    for (int am = 0; am < 4; ++am)
#pragma unroll
      for (int bp = 0; bp < 2; ++bp) {
        int col = n0 + wc * 64 + bp * 16 + c;  // j = col&63 in [0,32)
        int h = col >> 6, j = col & 63;
#pragma unroll
        for (int r = 0; r < 4; ++r) {
          int row = m0 + wr * 64 + am * 16 + (g << 2) + r;
          int b = row >> 11, s = row & 2047;
          float x1 = acc[am][bp][r], x2 = acc[am][bp + 2][r];
          float sn = rsin[s * 32 + j], cs = rcos[s * 32 + j];
          float o1 = cs * x1 - sn * x2;
          float o2 = sn * x1 + cs * x2;
          if (MODE == 0) { o1 *= 0.125f; o2 *= 0.125f; }
          size_t base = (((size_t)(b * 16 + h)) * 2048 + s) * 64;
          outb[base + j] = f2bf(o1);
          outb[base + 32 + j] = f2bf(o2);
        }
      }
  } else if (MODE == 2) {
    unsigned short* outb = (unsigned short*)outp;
#pragma unroll
    for (int am = 0; am < 4; ++am)
#pragma unroll
      for (int bn = 0; bn < 4; ++bn) {
        int col = n0 + wc * 64 + bn * 16 + c;
        int h = col >> 6, d = col & 63;
        int row0 = m0 + wr * 64 + am * 16 + (g << 2);
        int b = row0 >> 11, s0 = row0 & 2047;
        uint2 u;
        u.x = pack2bf(acc[am][bn][0], acc[am][bn][1]);
        u.y = pack2bf(acc[am][bn][2], acc[am][bn][3]);
        *(uint2*)(outb + ((size_t)((b * 16 + h) * 64 + d)) * 2048 + s0) = u;
      }
  } else {
    float* outf = (float*)outp;
#pragma unroll
    for (int am = 0; am < 4; ++am)
#pragma unroll
      for (int bn = 0; bn < 4; ++bn)
#pragma unroll
        for (int r = 0; r < 4; ++r)
          outf[(size_t)(m0 + wr * 64 + am * 16 + (g << 2) + r) * 1024 +
               (n0 + wc * 64 + bn * 16 + c)] = acc[am][bn][r];
  }
}

// ---------------- flash attention (causal) ----------------
// Q,K: [BH][2048][64] bf16 (Q pre-scaled by 0.125); VT: [BH][64][2048] bf16
// ctx out: [B][S][H*64] bf16.  4 waves x 16 q-rows, kv-steps of 64.
__global__ __launch_bounds__(256) void attn_k(
    const unsigned short* __restrict__ Q, const unsigned short* __restrict__ K,
    const unsigned short* __restrict__ VT, unsigned short* __restrict__ ctx) {
  __shared__ unsigned short Kt[64 * 64];
  __shared__ unsigned short Vt[64 * 64];
  __shared__ unsigned short Pl[4][16 * 64];
  const int qt = blockIdx.x, bh = blockIdx.y;
  const int tid = threadIdx.x;
  const int w = tid >> 6, lane = tid & 63, g = lane >> 4, c = lane & 15;
  const int qw = qt * 64 + w * 16;
  const unsigned short* Qbh = Q + (size_t)bh * 2048 * 64;
  const unsigned short* Kbh = K + (size_t)bh * 2048 * 64;
  const unsigned short* VTbh = VT + (size_t)bh * 64 * 2048;

  bf16x8 qf[2];
#pragma unroll
  for (int f = 0; f < 2; ++f)
    qf[f] = *(const bf16x8*)(Qbh + (size_t)(qw + c) * 64 + f * 32 + g * 8);

  f32x4 zero = {0.f, 0.f, 0.f, 0.f};
  f32x4 oacc[4];
#pragma unroll
  for (int nf = 0; nf < 4; ++nf) oacc[nf] = zero;
  float m_run = -1e30f, l_run = 0.f;

  const int nsteps = qt + 1;
  for (int st = 0; st < nsteps; ++st) {
    const int kv0 = st * 64;
#pragma unroll
    for (int p = 0; p < 2; ++p) {
      int i = p * 256 + tid;
      int row = i >> 3, ls = i & 7;
      gll16((const char*)Kbh + (size_t)(kv0 + row) * 128 + ((ls ^ (row & 7)) << 4),
            (char*)Kt + p * 4096 + w * 1024);
      gll16((const char*)VTbh + (size_t)row * 4096 + (size_t)kv0 * 2 +
                ((ls ^ (row & 7)) << 4),
            (char*)Vt + p * 4096 + w * 1024);
    }
    __syncthreads();

    // S^T = K_tile(64x64) . Q^T : frag t covers kv rows [t*16,t*16+16)
    f32x4 sacc[4];
#pragma unroll
    for (int t = 0; t < 4; ++t) sacc[t] = zero;
#pragma unroll
    for (int t = 0; t < 4; ++t) {
      int rowk = t * 16 + c;
#pragma unroll
      for (int f = 0; f < 2; ++f) {
        bf16x8 kf = *(const bf16x8*)(Kt + rowk * 64 + ((((f << 2) | g) ^ (c & 7)) << 3));
        sacc[t] = MFMA16(kf, qf[f], sacc[t]);
      }
    }
    // causal mask: kv = kv0 + t*16 + g*4 + r ; q = qw + c
    if (kv0 + 63 > qw) {
#pragma unroll
      for (int t = 0; t < 4; ++t)
#pragma unroll
        for (int r = 0; r < 4; ++r)
          if (kv0 + t * 16 + (g << 2) + r > qw + c) sacc[t][r] = -1e30f;
    }
    // online softmax (per q = c; reduce across lane bits 4,5)
    float vmax = -1e30f;
#pragma unroll
    for (int t = 0; t < 4; ++t)
#pragma unroll
      for (int r = 0; r < 4; ++r) vmax = fmaxf(vmax, sacc[t][r]);
    vmax = fmaxf(vmax, __shfl_xor(vmax, 16, 64));
    vmax = fmaxf(vmax, __shfl_xor(vmax, 32, 64));
    float m_new = fmaxf(m_run, vmax);
    float alpha = __expf(m_run - m_new);
    float psum = 0.f;
#pragma unroll
    for (int t = 0; t < 4; ++t)
#pragma unroll
      for (int r = 0; r < 4; ++r) {
        float pv = __expf(sacc[t][r] - m_new);
        sacc[t][r] = pv;
        psum += pv;
      }
    psum += __shfl_xor(psum, 16, 64);
    psum += __shfl_xor(psum, 32, 64);
    l_run = l_run * alpha + psum;
    m_run = m_new;

    // P (bf16) -> per-wave LDS, row q=c, 64 kv, XOR slot swizzle
    unsigned* Pw = (unsigned*)(&Pl[w][0]);
#pragma unroll
    for (int t = 0; t < 4; ++t)
#pragma unroll
      for (int h2 = 0; h2 < 2; ++h2) {
        unsigned val = pack2bf(sacc[t][2 * h2], sacc[t][2 * h2 + 1]);
        int boff = c * 128 + (((2 * t + (g >> 1)) ^ (c & 7)) << 4) + ((g & 1) << 3) + (h2 << 2);
        Pw[boff >> 2] = val;
      }
    // rescale O (rows q = g*4+r; alpha lives in lanes 0..15 at c=q)
#pragma unroll
    for (int r = 0; r < 4; ++r) {
      float ar = __shfl(alpha, (g << 2) | r, 64);
#pragma unroll
      for (int nf = 0; nf < 4; ++nf) oacc[nf][r] *= ar;
    }
    // PV: A = P[q][kv], B = V[kv][d] (from VT tile rows = d)
#pragma unroll
    for (int f = 0; f < 2; ++f) {
      bf16x8 pa = *(const bf16x8*)((const char*)(&Pl[w][0]) + c * 128 +
                                   ((((f << 2) | g) ^ (c & 7)) << 4));
#pragma unroll
      for (int nf = 0; nf < 4; ++nf) {
        int rowv = nf * 16 + c;
        bf16x8 vf = *(const bf16x8*)(Vt + rowv * 64 + ((((f << 2) | g) ^ (c & 7)) << 3));
        oacc[nf] = MFMA16(pa, vf, oacc[nf]);
      }
    }
    __syncthreads();
  }

  const int b = bh >> 4, h = bh & 15;
#pragma unroll
  for (int r = 0; r < 4; ++r) {
    float lv = __shfl(l_run, (g << 2) | r, 64);
    float linv = 1.f / lv;
    int q = qw + (g << 2) + r;
#pragma unroll
    for (int nf = 0; nf < 4; ++nf) {
      int d = nf * 16 + c;
      ctx[((size_t)(b * 2048 + q)) * 1024 + h * 64 + d] = f2bf(oacc[nf][r] * linv);
    }
  }
}

// ---------------- launcher ----------------

extern "C" void kernel_launch(void* const* d_in, const int* in_sizes, int n_in,
                              void* d_out, int out_size, void* d_ws, size_t ws_size,
                              hipStream_t stream) {
  (void)in_sizes; (void)n_in; (void)out_size; (void)ws_size;
  const float* x = (const float*)d_in[0];
  const float* Wq = (const float*)d_in[1];
  const float* Wk = (const float*)d_in[2];
  const float* Wv = (const float*)d_in[3];
  const float* Wo = (const float*)d_in[4];
  char* ws = (char*)d_ws;
  const size_t MiB = 1024 * 1024;
  unsigned short* xb  = (unsigned short*)(ws);             // 16 MiB
  unsigned short* WTq = (unsigned short*)(ws + 16 * MiB);  // 2 MiB each
  unsigned short* WTk = (unsigned short*)(ws + 18 * MiB);
  unsigned short* WTv = (unsigned short*)(ws + 20 * MiB);
  unsigned short* WTo = (unsigned short*)(ws + 22 * MiB);
  unsigned short* Qb  = (unsigned short*)(ws + 24 * MiB);  // 16 MiB each
  unsigned short* Kb  = (unsigned short*)(ws + 40 * MiB);
  unsigned short* VTb = (unsigned short*)(ws + 56 * MiB);
  unsigned short* ctx = (unsigned short*)(ws + 72 * MiB);
  float* rsin = (float*)(ws + 88 * MiB);                   // 256 KiB each
  float* rcos = (float*)(ws + 88 * MiB + 256 * 1024);

  conv_x_k<<<8192, 256, 0, stream>>>(x, xb);
  transp_k<<<dim3(16, 16, 4), 256, 0, stream>>>(Wq, Wk, Wv, Wo, WTq, WTk, WTv, WTo);
  rope_k<<<256, 256, 0, stream>>>(rsin, rcos);
  gemm_k<0><<<dim3(64, 8), 256, 0, stream>>>(xb, WTq, Qb, rsin, rcos);
  gemm_k<1><<<dim3(64, 8), 256, 0, stream>>>(xb, WTk, Kb, rsin, rcos);
  gemm_k<2><<<dim3(64, 8), 256, 0, stream>>>(xb, WTv, VTb, rsin, rcos);
  attn_k<<<dim3(32, 64), 256, 0, stream>>>(Qb, Kb, VTb, ctx);
  gemm_k<3><<<dim3(64, 8), 256, 0, stream>>>(ctx, WTo, d_out, rsin, rcos);
}

// Round 2
// 238.361 us; speedup vs baseline: 1.0734x; 1.0734x over previous
//
#include <hip/hip_runtime.h>

#define DEVFN __device__ __forceinline__

typedef __attribute__((ext_vector_type(8))) short bf16x8;
typedef __attribute__((ext_vector_type(4))) float f32x4;

#define MFMA16(a, b, c) __builtin_amdgcn_mfma_f32_16x16x32_bf16(a, b, c, 0, 0, 0)

DEVFN unsigned short f2bf(float f) {
  union { float f; unsigned u; } v; v.f = f;
  unsigned r = v.u + 0x7FFFu + ((v.u >> 16) & 1u);
  return (unsigned short)(r >> 16);
}
DEVFN unsigned pack2bf(float a, float b) {
  return (unsigned)f2bf(a) | ((unsigned)f2bf(b) << 16);
}
DEVFN void gll16(const void* g, void* l) {
  __builtin_amdgcn_global_load_lds((__attribute__((address_space(1))) void*)g,
                                   (__attribute__((address_space(3))) void*)l,
                                   16, 0, 0);
}

// ---------------- precompute kernels ----------------

__global__ __launch_bounds__(256) void conv_x_k(const float* __restrict__ x,
                                                unsigned short* __restrict__ xb) {
  int i = (blockIdx.x * 256 + threadIdx.x) * 4;
  float4 v = *(const float4*)(x + i);
  uint2 u;
  u.x = pack2bf(v.x, v.y);
  u.y = pack2bf(v.z, v.w);
  *(uint2*)(xb + i) = u;
}

// WT[n][k] = (bf16) W[k][n], 64x64 tiles through LDS
__global__ __launch_bounds__(256) void transp_k(
    const float* __restrict__ Wq, const float* __restrict__ Wk,
    const float* __restrict__ Wv, const float* __restrict__ Wo,
    unsigned short* __restrict__ Tq, unsigned short* __restrict__ Tk,
    unsigned short* __restrict__ Tv, unsigned short* __restrict__ To) {
  __shared__ unsigned short t[64 * 65];
  int z = blockIdx.z;
  const float* src = (z == 0) ? Wq : (z == 1) ? Wk : (z == 2) ? Wv : Wo;
  unsigned short* dst = (z == 0) ? Tq : (z == 1) ? Tk : (z == 2) ? Tv : To;
  int k0 = blockIdx.x * 64, n0 = blockIdx.y * 64;
  int tid = threadIdx.x;
#pragma unroll
  for (int i = 0; i < 16; ++i) {
    int flat = i * 256 + tid;
    int r = flat >> 6, cc = flat & 63;
    t[cc * 65 + r] = f2bf(src[(size_t)(k0 + r) * 1024 + n0 + cc]);
  }
  __syncthreads();
#pragma unroll
  for (int i = 0; i < 16; ++i) {
    int flat = i * 256 + tid;
    int rr = flat >> 6, cc = flat & 63;
    dst[(size_t)(n0 + rr) * 1024 + k0 + cc] = t[rr * 65 + cc];
  }
}

__global__ __launch_bounds__(256) void rope_k(float* __restrict__ rsin,
                                              float* __restrict__ rcos) {
  int idx = blockIdx.x * 256 + threadIdx.x;  // 2048*32
  int s = idx >> 5, j = idx & 31;
  float freq = expf(-0.28782313714981824f * (float)j);
  float ang = (float)s * freq;
  rsin[idx] = sinf(ang);
  rcos[idx] = cosf(ang);
}

// ---------------- GEMM: C[8192,1024] = A(bf16) @ W, B given as WT[n][k] ----
// MODE 0: Q epilogue (RoPE + 0.125*log2e scale) -> [BH][S][D] bf16
// MODE 1: K epilogue (RoPE)               -> [BH][S][D] bf16
// MODE 2: V epilogue (transposed)         -> [BH][D][S] bf16
// MODE 3: plain fp32                       -> d_out [8192][1024]
template <int MODE>
__global__ __launch_bounds__(256) void gemm_k(
    const unsigned short* __restrict__ A, const unsigned short* __restrict__ WT,
    void* __restrict__ outp, const float* __restrict__ rsin,
    const float* __restrict__ rcos) {
  __shared__ unsigned short At[128 * 64];
  __shared__ unsigned short Bt[128 * 64];
  const int tid = threadIdx.x;
  const int w = tid >> 6, lane = tid & 63, g = lane >> 4, c = lane & 15;
  const int wr = w >> 1, wc = w & 1;
  const int m0 = blockIdx.x * 128, n0 = blockIdx.y * 128;

  f32x4 zero = {0.f, 0.f, 0.f, 0.f};
  f32x4 acc[4][4];
#pragma unroll
  for (int i = 0; i < 4; ++i)
#pragma unroll
    for (int j = 0; j < 4; ++j) acc[i][j] = zero;

  for (int k0 = 0; k0 < 1024; k0 += 64) {
#pragma unroll
    for (int p = 0; p < 4; ++p) {
      int i = p * 256 + tid;
      int row = i >> 3, ls = i & 7;
      size_t off = ((size_t)(m0 + row) * 1024 + k0) * 2 + ((ls ^ (row & 7)) << 4);
      gll16((const char*)A + off, (char*)At + p * 4096 + w * 1024);
      size_t offb = ((size_t)(n0 + row) * 1024 + k0) * 2 + ((ls ^ (row & 7)) << 4);
      gll16((const char*)WT + offb, (char*)Bt + p * 4096 + w * 1024);
    }
    __syncthreads();
#pragma unroll
    for (int ks = 0; ks < 2; ++ks) {
      bf16x8 af[4], bfv[4];
#pragma unroll
      for (int am = 0; am < 4; ++am) {
        int row = wr * 64 + am * 16 + c;
        af[am] = *(const bf16x8*)(At + row * 64 + ((((ks << 2) | g) ^ (row & 7)) << 3));
      }
#pragma unroll
      for (int bn = 0; bn < 4; ++bn) {
        int row = wc * 64 + bn * 16 + c;
        bfv[bn] = *(const bf16x8*)(Bt + row * 64 + ((((ks << 2) | g) ^ (row & 7)) << 3));
      }
#pragma unroll
      for (int am = 0; am < 4; ++am)
#pragma unroll
        for (int bn = 0; bn < 4; ++bn)
          acc[am][bn] = MFMA16(af[am], bfv[bn], acc[am][bn]);
    }
    __syncthreads();
  }

  if (MODE == 0 || MODE == 1) {
    unsigned short* outb = (unsigned short*)outp;
#pragma unroll
    for (int am = 0; am < 4; ++am)
#pragma unroll
      for (int bp = 0; bp < 2; ++bp) {
        int col = n0 + wc * 64 + bp * 16 + c;
        int h = col >> 6, j = col & 63;
#pragma unroll
        for (int r = 0; r < 4; ++r) {
          int row = m0 + wr * 64 + am * 16 + (g << 2) + r;
          int b = row >> 11, s = row & 2047;
          float x1 = acc[am][bp][r], x2 = acc[am][bp + 2][r];
          float sn = rsin[s * 32 + j], cs = rcos[s * 32 + j];
          float o1 = cs * x1 - sn * x2;
          float o2 = sn * x1 + cs * x2;
          if (MODE == 0) {
            o1 *= 0.18033688011112042f;  // 0.125 * log2(e): scores in log2 domain
            o2 *= 0.18033688011112042f;
          }
          size_t base = (((size_t)(b * 16 + h)) * 2048 + s) * 64;
          outb[base + j] = f2bf(o1);
          outb[base + 32 + j] = f2bf(o2);
        }
      }
  } else if (MODE == 2) {
    unsigned short* outb = (unsigned short*)outp;
#pragma unroll
    for (int am = 0; am < 4; ++am)
#pragma unroll
      for (int bn = 0; bn < 4; ++bn) {
        int col = n0 + wc * 64 + bn * 16 + c;
        int h = col >> 6, d = col & 63;
        int row0 = m0 + wr * 64 + am * 16 + (g << 2);
        int b = row0 >> 11, s0 = row0 & 2047;
        uint2 u;
        u.x = pack2bf(acc[am][bn][0], acc[am][bn][1]);
        u.y = pack2bf(acc[am][bn][2], acc[am][bn][3]);
        *(uint2*)(outb + ((size_t)((b * 16 + h) * 64 + d)) * 2048 + s0) = u;
      }
  } else {
    float* outf = (float*)outp;
#pragma unroll
    for (int am = 0; am < 4; ++am)
#pragma unroll
      for (int bn = 0; bn < 4; ++bn)
#pragma unroll
        for (int r = 0; r < 4; ++r)
          outf[(size_t)(m0 + wr * 64 + am * 16 + (g << 2) + r) * 1024 +
               (n0 + wc * 64 + bn * 16 + c)] = acc[am][bn][r];
  }
}

// ---------------- flash attention (causal, paired-tile load-balanced) ------
// Q,K: [BH][2048][64] bf16 (Q pre-scaled by 0.125*log2e); VT: [BH][64][2048]
// ctx out: [B][S][H*64] bf16.
// Each block: q-tiles A=p (64 rows) and B=31-p; A's kv range is a prefix of
// B's, so both share the staged K/V tile. Every block = 33 compute-units.
// K/V double-buffered, prefetch issued before compute (one barrier/step).
__global__ __launch_bounds__(256, 4) void attn_k(
    const unsigned short* __restrict__ Q, const unsigned short* __restrict__ K,
    const unsigned short* __restrict__ VT, unsigned short* __restrict__ ctx) {
  __shared__ unsigned short Kt[2][64 * 64];
  __shared__ unsigned short Vt[2][64 * 64];
  __shared__ unsigned short Pl[4][16 * 64];

  // XCD swizzle: fid%8 = XCD (round-robin dispatch) -> each XCD owns 8 heads
  const int fid = blockIdx.x + (blockIdx.y << 4);
  const int xcd = fid & 7, j = fid >> 3;
  const int bh = (xcd << 3) + (j >> 4);
  const int p = j & 15;
  const int qtB = 31 - p;

  const int tid = threadIdx.x;
  const int w = tid >> 6, lane = tid & 63, g = lane >> 4, c = lane & 15;
  const int qwA = p * 64 + w * 16;
  const int qwB = qtB * 64 + w * 16;
  const unsigned short* Qbh = Q + (size_t)bh * 2048 * 64;
  const unsigned short* Kbh = K + (size_t)bh * 2048 * 64;
  const unsigned short* VTbh = VT + (size_t)bh * 64 * 2048;
  unsigned short* Pw = &Pl[w][0];

  bf16x8 qfA[2], qfB[2];
#pragma unroll
  for (int f = 0; f < 2; ++f) {
    qfA[f] = *(const bf16x8*)(Qbh + (size_t)(qwA + c) * 64 + f * 32 + g * 8);
    qfB[f] = *(const bf16x8*)(Qbh + (size_t)(qwB + c) * 64 + f * 32 + g * 8);
  }

  f32x4 zero = {0.f, 0.f, 0.f, 0.f};
  f32x4 oaccA[4], oaccB[4];
#pragma unroll
  for (int nf = 0; nf < 4; ++nf) { oaccA[nf] = zero; oaccB[nf] = zero; }
  float mA = -1e30f, lA = 0.f, mB = -1e30f, lB = 0.f;

  auto stage = [&](int st, int buf) {
    const int kv0 = st * 64;
#pragma unroll
    for (int pp = 0; pp < 2; ++pp) {
      int i = pp * 256 + tid;
      int row = i >> 3, ls = i & 7;
      gll16((const char*)Kbh + (size_t)(kv0 + row) * 128 + ((ls ^ (row & 7)) << 4),
            (char*)(&Kt[buf][0]) + pp * 4096 + w * 1024);
      gll16((const char*)VTbh + (size_t)row * 4096 + (size_t)kv0 * 2 +
                ((ls ^ (row & 7)) << 4),
            (char*)(&Vt[buf][0]) + pp * 4096 + w * 1024);
    }
  };

  auto tile_compute = [&](int qw, const bf16x8* qf, f32x4* oacc, float& m_run,
                          float& l_run, const unsigned short* Ktb,
                          const unsigned short* Vtb, int kv0, bool domask) {
    f32x4 sacc[4];
#pragma unroll
    for (int t = 0; t < 4; ++t) sacc[t] = zero;
#pragma unroll
    for (int t = 0; t < 4; ++t) {
      int rowk = t * 16 + c;
#pragma unroll
      for (int f = 0; f < 2; ++f) {
        bf16x8 kf = *(const bf16x8*)(Ktb + rowk * 64 + ((((f << 2) | g) ^ (c & 7)) << 3));
        sacc[t] = MFMA16(kf, qf[f], sacc[t]);
      }
    }
    if (domask) {
#pragma unroll
      for (int t = 0; t < 4; ++t)
#pragma unroll
        for (int r = 0; r < 4; ++r)
          if (kv0 + t * 16 + (g << 2) + r > qw + c) sacc[t][r] = -1e30f;
    }
    float vmax = -1e30f;
#pragma unroll
    for (int t = 0; t < 4; ++t)
#pragma unroll
      for (int r = 0; r < 4; ++r) vmax = fmaxf(vmax, sacc[t][r]);
    vmax = fmaxf(vmax, __shfl_xor(vmax, 16, 64));
    vmax = fmaxf(vmax, __shfl_xor(vmax, 32, 64));
    float m_new = fmaxf(m_run, vmax);
    float alpha = exp2f(m_run - m_new);
    float psum = 0.f;
#pragma unroll
    for (int t = 0; t < 4; ++t)
#pragma unroll
      for (int r = 0; r < 4; ++r) {
        float pv = exp2f(sacc[t][r] - m_new);
        sacc[t][r] = pv;
        psum += pv;
      }
    psum += __shfl_xor(psum, 16, 64);
    psum += __shfl_xor(psum, 32, 64);
    l_run = l_run * alpha + psum;
    m_run = m_new;

    unsigned* Pu = (unsigned*)Pw;
#pragma unroll
    for (int t = 0; t < 4; ++t)
#pragma unroll
      for (int h2 = 0; h2 < 2; ++h2) {
        unsigned val = pack2bf(sacc[t][2 * h2], sacc[t][2 * h2 + 1]);
        int boff = c * 128 + (((2 * t + (g >> 1)) ^ (c & 7)) << 4) + ((g & 1) << 3) + (h2 << 2);
        Pu[boff >> 2] = val;
      }
#pragma unroll
    for (int r = 0; r < 4; ++r) {
      float ar = __shfl(alpha, (g << 2) | r, 64);
#pragma unroll
      for (int nf = 0; nf < 4; ++nf) oacc[nf][r] *= ar;
    }
#pragma unroll
    for (int f = 0; f < 2; ++f) {
      bf16x8 pa = *(const bf16x8*)((const char*)Pw + c * 128 +
                                   ((((f << 2) | g) ^ (c & 7)) << 4));
#pragma unroll
      for (int nf = 0; nf < 4; ++nf) {
        int rowv = nf * 16 + c;
        bf16x8 vf = *(const bf16x8*)(Vtb + rowv * 64 + ((((f << 2) | g) ^ (c & 7)) << 3));
        oacc[nf] = MFMA16(pa, vf, oacc[nf]);
      }
    }
  };

  const int last = qtB;  // steps 0..last
  stage(0, 0);
  __syncthreads();
  for (int st = 0; st <= last; ++st) {
    const int cur = st & 1;
    if (st < last) stage(st + 1, cur ^ 1);
    const int kv0 = st * 64;
    tile_compute(qwB, qfB, oaccB, mB, lB, &Kt[cur][0], &Vt[cur][0], kv0, st == qtB);
    if (st <= p)
      tile_compute(qwA, qfA, oaccA, mA, lA, &Kt[cur][0], &Vt[cur][0], kv0, st == p);
    __syncthreads();
  }

  const int b = bh >> 4, h = bh & 15;
#pragma unroll
  for (int r = 0; r < 4; ++r) {
    float lvA = __shfl(lA, (g << 2) | r, 64);
    float lvB = __shfl(lB, (g << 2) | r, 64);
    float liA = 1.f / lvA, liB = 1.f / lvB;
    int qA = qwA + (g << 2) + r;
    int qB = qwB + (g << 2) + r;
#pragma unroll
    for (int nf = 0; nf < 4; ++nf) {
      int d = nf * 16 + c;
      ctx[((size_t)(b * 2048 + qA)) * 1024 + h * 64 + d] = f2bf(oaccA[nf][r] * liA);
      ctx[((size_t)(b * 2048 + qB)) * 1024 + h * 64 + d] = f2bf(oaccB[nf][r] * liB);
    }
  }
}

// ---------------- launcher ----------------

extern "C" void kernel_launch(void* const* d_in, const int* in_sizes, int n_in,
                              void* d_out, int out_size, void* d_ws, size_t ws_size,
                              hipStream_t stream) {
  (void)in_sizes; (void)n_in; (void)out_size; (void)ws_size;
  const float* x = (const float*)d_in[0];
  const float* Wq = (const float*)d_in[1];
  const float* Wk = (const float*)d_in[2];
  const float* Wv = (const float*)d_in[3];
  const float* Wo = (const float*)d_in[4];
  char* ws = (char*)d_ws;
  const size_t MiB = 1024 * 1024;
  unsigned short* xb  = (unsigned short*)(ws);             // 16 MiB
  unsigned short* WTq = (unsigned short*)(ws + 16 * MiB);  // 2 MiB each
  unsigned short* WTk = (unsigned short*)(ws + 18 * MiB);
  unsigned short* WTv = (unsigned short*)(ws + 20 * MiB);
  unsigned short* WTo = (unsigned short*)(ws + 22 * MiB);
  unsigned short* Qb  = (unsigned short*)(ws + 24 * MiB);  // 16 MiB each
  unsigned short* Kb  = (unsigned short*)(ws + 40 * MiB);
  unsigned short* VTb = (unsigned short*)(ws + 56 * MiB);
  unsigned short* ctx = (unsigned short*)(ws + 72 * MiB);
  float* rsin = (float*)(ws + 88 * MiB);                   // 256 KiB each
  float* rcos = (float*)(ws + 88 * MiB + 256 * 1024);

  conv_x_k<<<8192, 256, 0, stream>>>(x, xb);
  transp_k<<<dim3(16, 16, 4), 256, 0, stream>>>(Wq, Wk, Wv, Wo, WTq, WTk, WTv, WTo);
  rope_k<<<256, 256, 0, stream>>>(rsin, rcos);
  gemm_k<0><<<dim3(64, 8), 256, 0, stream>>>(xb, WTq, Qb, rsin, rcos);
  gemm_k<1><<<dim3(64, 8), 256, 0, stream>>>(xb, WTk, Kb, rsin, rcos);
  gemm_k<2><<<dim3(64, 8), 256, 0, stream>>>(xb, WTv, VTb, rsin, rcos);
  attn_k<<<dim3(16, 64), 256, 0, stream>>>(Qb, Kb, VTb, ctx);
  gemm_k<3><<<dim3(64, 8), 256, 0, stream>>>(ctx, WTo, d_out, rsin, rcos);
}

// Round 3
// 199.021 us; speedup vs baseline: 1.2856x; 1.1977x over previous
//
#include <hip/hip_runtime.h>

#define DEVFN __device__ __forceinline__

typedef __attribute__((ext_vector_type(8))) short bf16x8;
typedef __attribute__((ext_vector_type(4))) float f32x4;
typedef __attribute__((ext_vector_type(16))) float f32x16;

#define MFMA16(a, b, c) __builtin_amdgcn_mfma_f32_16x16x32_bf16(a, b, c, 0, 0, 0)
#define MFMA32(a, b, c) __builtin_amdgcn_mfma_f32_32x32x16_bf16(a, b, c, 0, 0, 0)

DEVFN unsigned short f2bf(float f) {
  union { float f; unsigned u; } v; v.f = f;
  unsigned r = v.u + 0x7FFFu + ((v.u >> 16) & 1u);
  return (unsigned short)(r >> 16);
}
DEVFN unsigned pack2bf(float a, float b) {
  return (unsigned)f2bf(a) | ((unsigned)f2bf(b) << 16);
}
DEVFN unsigned cvtpk(float lo, float hi) {
  unsigned r;
  asm("v_cvt_pk_bf16_f32 %0, %1, %2" : "=v"(r) : "v"(lo), "v"(hi));
  return r;
}
DEVFN void pl32swap(unsigned& a, unsigned& b) {
  asm("v_permlane32_swap_b32 %0, %1" : "+v"(a), "+v"(b));
}
DEVFN void gll16(const void* g, void* l) {
  __builtin_amdgcn_global_load_lds((__attribute__((address_space(1))) void*)g,
                                   (__attribute__((address_space(3))) void*)l,
                                   16, 0, 0);
}

// ---------------- precompute kernels ----------------

__global__ __launch_bounds__(256) void conv_x_k(const float* __restrict__ x,
                                                unsigned short* __restrict__ xb) {
  int i = (blockIdx.x * 256 + threadIdx.x) * 4;
  float4 v = *(const float4*)(x + i);
  uint2 u;
  u.x = pack2bf(v.x, v.y);
  u.y = pack2bf(v.z, v.w);
  *(uint2*)(xb + i) = u;
}

// WT[n][k] = (bf16) W[k][n], 64x64 tiles through LDS
__global__ __launch_bounds__(256) void transp_k(
    const float* __restrict__ Wq, const float* __restrict__ Wk,
    const float* __restrict__ Wv, const float* __restrict__ Wo,
    unsigned short* __restrict__ Tq, unsigned short* __restrict__ Tk,
    unsigned short* __restrict__ Tv, unsigned short* __restrict__ To) {
  __shared__ unsigned short t[64 * 65];
  int z = blockIdx.z;
  const float* src = (z == 0) ? Wq : (z == 1) ? Wk : (z == 2) ? Wv : Wo;
  unsigned short* dst = (z == 0) ? Tq : (z == 1) ? Tk : (z == 2) ? Tv : To;
  int k0 = blockIdx.x * 64, n0 = blockIdx.y * 64;
  int tid = threadIdx.x;
#pragma unroll
  for (int i = 0; i < 16; ++i) {
    int flat = i * 256 + tid;
    int r = flat >> 6, cc = flat & 63;
    t[cc * 65 + r] = f2bf(src[(size_t)(k0 + r) * 1024 + n0 + cc]);
  }
  __syncthreads();
#pragma unroll
  for (int i = 0; i < 16; ++i) {
    int flat = i * 256 + tid;
    int rr = flat >> 6, cc = flat & 63;
    dst[(size_t)(n0 + rr) * 1024 + k0 + cc] = t[rr * 65 + cc];
  }
}

__global__ __launch_bounds__(256) void rope_k(float* __restrict__ rsin,
                                              float* __restrict__ rcos) {
  int idx = blockIdx.x * 256 + threadIdx.x;  // 2048*32
  int s = idx >> 5, j = idx & 31;
  float freq = expf(-0.28782313714981824f * (float)j);
  float ang = (float)s * freq;
  rsin[idx] = sinf(ang);
  rcos[idx] = cosf(ang);
}

// ---------------- GEMM: C[8192,1024] = A(bf16) @ W, B given as WT[n][k] ----
template <int MODE>
__global__ __launch_bounds__(256) void gemm_k(
    const unsigned short* __restrict__ A, const unsigned short* __restrict__ WT,
    void* __restrict__ outp, const float* __restrict__ rsin,
    const float* __restrict__ rcos) {
  __shared__ unsigned short At[128 * 64];
  __shared__ unsigned short Bt[128 * 64];
  const int tid = threadIdx.x;
  const int w = tid >> 6, lane = tid & 63, g = lane >> 4, c = lane & 15;
  const int wr = w >> 1, wc = w & 1;
  const int m0 = blockIdx.x * 128, n0 = blockIdx.y * 128;

  f32x4 zero = {0.f, 0.f, 0.f, 0.f};
  f32x4 acc[4][4];
#pragma unroll
  for (int i = 0; i < 4; ++i)
#pragma unroll
    for (int j = 0; j < 4; ++j) acc[i][j] = zero;

  for (int k0 = 0; k0 < 1024; k0 += 64) {
#pragma unroll
    for (int p = 0; p < 4; ++p) {
      int i = p * 256 + tid;
      int row = i >> 3, ls = i & 7;
      size_t off = ((size_t)(m0 + row) * 1024 + k0) * 2 + ((ls ^ (row & 7)) << 4);
      gll16((const char*)A + off, (char*)At + p * 4096 + w * 1024);
      size_t offb = ((size_t)(n0 + row) * 1024 + k0) * 2 + ((ls ^ (row & 7)) << 4);
      gll16((const char*)WT + offb, (char*)Bt + p * 4096 + w * 1024);
    }
    __syncthreads();
#pragma unroll
    for (int ks = 0; ks < 2; ++ks) {
      bf16x8 af[4], bfv[4];
#pragma unroll
      for (int am = 0; am < 4; ++am) {
        int row = wr * 64 + am * 16 + c;
        af[am] = *(const bf16x8*)(At + row * 64 + ((((ks << 2) | g) ^ (row & 7)) << 3));
      }
#pragma unroll
      for (int bn = 0; bn < 4; ++bn) {
        int row = wc * 64 + bn * 16 + c;
        bfv[bn] = *(const bf16x8*)(Bt + row * 64 + ((((ks << 2) | g) ^ (row & 7)) << 3));
      }
#pragma unroll
      for (int am = 0; am < 4; ++am)
#pragma unroll
        for (int bn = 0; bn < 4; ++bn)
          acc[am][bn] = MFMA16(af[am], bfv[bn], acc[am][bn]);
    }
    __syncthreads();
  }

  if (MODE == 0 || MODE == 1) {
    unsigned short* outb = (unsigned short*)outp;
#pragma unroll
    for (int am = 0; am < 4; ++am)
#pragma unroll
      for (int bp = 0; bp < 2; ++bp) {
        int col = n0 + wc * 64 + bp * 16 + c;
        int h = col >> 6, j = col & 63;
#pragma unroll
        for (int r = 0; r < 4; ++r) {
          int row = m0 + wr * 64 + am * 16 + (g << 2) + r;
          int b = row >> 11, s = row & 2047;
          float x1 = acc[am][bp][r], x2 = acc[am][bp + 2][r];
          float sn = rsin[s * 32 + j], cs = rcos[s * 32 + j];
          float o1 = cs * x1 - sn * x2;
          float o2 = sn * x1 + cs * x2;
          if (MODE == 0) {
            o1 *= 0.18033688011112042f;  // 0.125 * log2(e)
            o2 *= 0.18033688011112042f;
          }
          size_t base = (((size_t)(b * 16 + h)) * 2048 + s) * 64;
          outb[base + j] = f2bf(o1);
          outb[base + 32 + j] = f2bf(o2);
        }
      }
  } else if (MODE == 2) {
    unsigned short* outb = (unsigned short*)outp;
#pragma unroll
    for (int am = 0; am < 4; ++am)
#pragma unroll
      for (int bn = 0; bn < 4; ++bn) {
        int col = n0 + wc * 64 + bn * 16 + c;
        int h = col >> 6, d = col & 63;
        int row0 = m0 + wr * 64 + am * 16 + (g << 2);
        int b = row0 >> 11, s0 = row0 & 2047;
        uint2 u;
        u.x = pack2bf(acc[am][bn][0], acc[am][bn][1]);
        u.y = pack2bf(acc[am][bn][2], acc[am][bn][3]);
        *(uint2*)(outb + ((size_t)((b * 16 + h) * 64 + d)) * 2048 + s0) = u;
      }
  } else {
    float* outf = (float*)outp;
#pragma unroll
    for (int am = 0; am < 4; ++am)
#pragma unroll
      for (int bn = 0; bn < 4; ++bn)
#pragma unroll
        for (int r = 0; r < 4; ++r)
          outf[(size_t)(m0 + wr * 64 + am * 16 + (g << 2) + r) * 1024 +
               (n0 + wc * 64 + bn * 16 + c)] = acc[am][bn][r];
  }
}

// ---------------- flash attention (causal, 32x32 MFMA, in-reg softmax) -----
// Q,K: [BH][2048][64] bf16 (Q pre-scaled by 0.125*log2e); VT: [BH][64][2048]
// ctx: [B][S][H*64] bf16.
// Block: 4 waves. Wave pair (w>>1) handles one 64-row q-tile (A=p or B=31-p,
// alternated by block parity for SIMD balance); each wave owns 32 q-rows.
// Swapped QK^T (mfma32(K,Q)) -> q is lane-local (col=lane&31): softmax m/l/
// alpha per-lane scalars, rescale shuffle-free. P redistributed to the PV
// B-fragment in-register via 16 cvt_pk + 8 permlane32_swap (no LDS).
__global__ __launch_bounds__(256, 4) void attn_k(
    const unsigned short* __restrict__ Q, const unsigned short* __restrict__ K,
    const unsigned short* __restrict__ VT, unsigned short* __restrict__ ctx) {
  __shared__ unsigned short Kt[2][64 * 64];
  __shared__ unsigned short Vt[2][64 * 64];

  const int fid = blockIdx.x + (blockIdx.y << 4);
  const int xcd = fid & 7, j = fid >> 3;
  const int bh = (xcd << 3) + (j >> 4);  // 8 heads per XCD (K/V L2-resident)
  const int p = j & 15;
  const int qtB = 31 - p;

  const int tid = threadIdx.x;
  const int w = tid >> 6, lane = tid & 63;
  const int hi = lane >> 5, c5 = lane & 31;
  const int myIsB = ((w >> 1) == (fid & 1));
  const int myTile = myIsB ? qtB : p;
  const int myLast = myTile;                      // last active kv step
  const int qw = myTile * 64 + (w & 1) * 32;      // this wave's 32 q-rows

  const unsigned short* Qbh = Q + (size_t)bh * 2048 * 64;
  const unsigned short* Kbh = K + (size_t)bh * 2048 * 64;
  const unsigned short* VTbh = VT + (size_t)bh * 64 * 2048;

  // Q fragment: B-operand of mfma32: B[k=dk][col=q]: lane holds
  // Q[qw+c5][kb*16 + hi*8 + j], j=0..7
  bf16x8 qf[4];
#pragma unroll
  for (int kb = 0; kb < 4; ++kb)
    qf[kb] = *(const bf16x8*)(Qbh + (size_t)(qw + c5) * 64 + kb * 16 + hi * 8);

  f32x16 oacc[2];
#pragma unroll
  for (int dt = 0; dt < 2; ++dt)
#pragma unroll
    for (int i = 0; i < 16; ++i) oacc[dt][i] = 0.f;
  float m_run = -1e30f, l_run = 0.f;

  auto stage = [&](int st, int buf) {
    const int kv0 = st * 64;
#pragma unroll
    for (int pp = 0; pp < 2; ++pp) {
      int i = pp * 256 + tid;
      int row = i >> 3, ls = i & 7;
      gll16((const char*)Kbh + (size_t)(kv0 + row) * 128 + ((ls ^ (row & 7)) << 4),
            (char*)(&Kt[buf][0]) + pp * 4096 + w * 1024);
      gll16((const char*)VTbh + (size_t)row * 4096 + (size_t)kv0 * 2 +
                ((ls ^ (row & 7)) << 4),
            (char*)(&Vt[buf][0]) + pp * 4096 + w * 1024);
    }
  };

  stage(0, 0);
  __syncthreads();

  for (int st = 0; st <= qtB; ++st) {
    const int cur = st & 1;
    if (st < qtB) stage(st + 1, cur ^ 1);

    if (st <= myLast) {
      const unsigned short* Kb_ = &Kt[cur][0];
      const unsigned short* Vb_ = &Vt[cur][0];

      // QK^T: sacc[t] = S^T[kv = st*64 + t*32 + row][q = qw + c5]
      f32x16 sacc[2];
#pragma unroll
      for (int t = 0; t < 2; ++t)
#pragma unroll
        for (int i = 0; i < 16; ++i) sacc[t][i] = 0.f;
#pragma unroll
      for (int t = 0; t < 2; ++t) {
        const int row = t * 32 + c5;
#pragma unroll
        for (int kb = 0; kb < 4; ++kb) {
          bf16x8 kf = *(const bf16x8*)(Kb_ + row * 64 +
                                       (((2 * kb + hi) ^ (c5 & 7)) << 3));
          sacc[t] = MFMA32(kf, qf[kb], sacc[t]);
        }
      }

      // causal mask (diagonal step only): kv = st*64+t*32+(i&3)+8*(i>>2)+4*hi
      if (st == myLast) {
        const int q = qw + c5;
#pragma unroll
        for (int t = 0; t < 2; ++t) {
          const int kvb = st * 64 + t * 32 + (hi << 2);
#pragma unroll
          for (int i = 0; i < 16; ++i) {
            int kv = kvb + (i & 3) + ((i >> 2) << 3);
            if (kv > q) sacc[t][i] = -1e30f;
          }
        }
      }

      // online softmax: q lane-local; row split across hi halves only
      float vmax = -1e30f;
#pragma unroll
      for (int t = 0; t < 2; ++t)
#pragma unroll
        for (int i = 0; i < 16; ++i) vmax = fmaxf(vmax, sacc[t][i]);
      vmax = fmaxf(vmax, __shfl_xor(vmax, 32, 64));
      if (!__all(vmax <= m_run + 8.0f)) {  // defer-max (log2 domain, THR=8)
        float m_new = fmaxf(m_run, vmax);
        float alpha = exp2f(m_run - m_new);
        l_run *= alpha;
#pragma unroll
        for (int dt = 0; dt < 2; ++dt)
#pragma unroll
          for (int i = 0; i < 16; ++i) oacc[dt][i] *= alpha;
        m_run = m_new;
      }
      float psum = 0.f;
#pragma unroll
      for (int t = 0; t < 2; ++t)
#pragma unroll
        for (int i = 0; i < 16; ++i) {
          float pv = exp2f(sacc[t][i] - m_run);
          sacc[t][i] = pv;
          psum += pv;
        }
      psum += __shfl_xor(psum, 32, 64);
      l_run += psum;

      // P -> bf16 PV B-fragments in-register: 16 cvt_pk + 8 permlane32_swap
      unsigned pword[4][4];  // [kb][word]
#pragma unroll
      for (int t = 0; t < 2; ++t) {
        unsigned X[4][2];
#pragma unroll
        for (int u = 0; u < 4; ++u)
#pragma unroll
          for (int wp = 0; wp < 2; ++wp)
            X[u][wp] = cvtpk(sacc[t][u * 4 + 2 * wp], sacc[t][u * 4 + 2 * wp + 1]);
#pragma unroll
        for (int par = 0; par < 2; ++par) {
          const int kb = 2 * t + par;
#pragma unroll
          for (int wp = 0; wp < 2; ++wp) {
            unsigned a = X[2 * par][wp], b2 = X[2 * par + 1][wp];
            pl32swap(a, b2);
            pword[kb][wp] = a;       // k-pair j = 2wp, 2wp+1
            pword[kb][wp + 2] = b2;  // k-pair j = 4+2wp, 4+2wp+1
          }
        }
      }

      // PV: O^T[d][q] += V^T[d][kv] . P[kv][q]
#pragma unroll
      for (int kb = 0; kb < 4; ++kb) {
        union { unsigned u[4]; bf16x8 v; } pw;
#pragma unroll
        for (int k2 = 0; k2 < 4; ++k2) pw.u[k2] = pword[kb][k2];
#pragma unroll
        for (int dt = 0; dt < 2; ++dt) {
          const int row = dt * 32 + c5;
          bf16x8 vf = *(const bf16x8*)(Vb_ + row * 64 +
                                       (((2 * kb + hi) ^ (c5 & 7)) << 3));
          oacc[dt] = MFMA32(vf, pw.v, oacc[dt]);
        }
      }
    }
    __syncthreads();
  }

  // epilogue: O^T[d][q]/l -> ctx[b][q][h*64+d]; d runs of 4 -> 8B stores
  const int b = bh >> 4, h = bh & 15;
  const float linv = 1.f / l_run;
  unsigned short* crow = ctx + ((size_t)(b * 2048 + qw + c5)) * 1024 + h * 64;
#pragma unroll
  for (int dt = 0; dt < 2; ++dt)
#pragma unroll
    for (int u = 0; u < 4; ++u) {
      int d0 = dt * 32 + 8 * u + 4 * hi;
      uint2 o;
      o.x = cvtpk(oacc[dt][4 * u] * linv, oacc[dt][4 * u + 1] * linv);
      o.y = cvtpk(oacc[dt][4 * u + 2] * linv, oacc[dt][4 * u + 3] * linv);
      *(uint2*)(crow + d0) = o;
    }
}

// ---------------- launcher ----------------

extern "C" void kernel_launch(void* const* d_in, const int* in_sizes, int n_in,
                              void* d_out, int out_size, void* d_ws, size_t ws_size,
                              hipStream_t stream) {
  (void)in_sizes; (void)n_in; (void)out_size; (void)ws_size;
  const float* x = (const float*)d_in[0];
  const float* Wq = (const float*)d_in[1];
  const float* Wk = (const float*)d_in[2];
  const float* Wv = (const float*)d_in[3];
  const float* Wo = (const float*)d_in[4];
  char* ws = (char*)d_ws;
  const size_t MiB = 1024 * 1024;
  unsigned short* xb  = (unsigned short*)(ws);             // 16 MiB
  unsigned short* WTq = (unsigned short*)(ws + 16 * MiB);  // 2 MiB each
  unsigned short* WTk = (unsigned short*)(ws + 18 * MiB);
  unsigned short* WTv = (unsigned short*)(ws + 20 * MiB);
  unsigned short* WTo = (unsigned short*)(ws + 22 * MiB);
  unsigned short* Qb  = (unsigned short*)(ws + 24 * MiB);  // 16 MiB each
  unsigned short* Kb  = (unsigned short*)(ws + 40 * MiB);
  unsigned short* VTb = (unsigned short*)(ws + 56 * MiB);
  unsigned short* ctx = (unsigned short*)(ws + 72 * MiB);
  float* rsin = (float*)(ws + 88 * MiB);                   // 256 KiB each
  float* rcos = (float*)(ws + 88 * MiB + 256 * 1024);

  conv_x_k<<<8192, 256, 0, stream>>>(x, xb);
  transp_k<<<dim3(16, 16, 4), 256, 0, stream>>>(Wq, Wk, Wv, Wo, WTq, WTk, WTv, WTo);
  rope_k<<<256, 256, 0, stream>>>(rsin, rcos);
  gemm_k<0><<<dim3(64, 8), 256, 0, stream>>>(xb, WTq, Qb, rsin, rcos);
  gemm_k<1><<<dim3(64, 8), 256, 0, stream>>>(xb, WTk, Kb, rsin, rcos);
  gemm_k<2><<<dim3(64, 8), 256, 0, stream>>>(xb, WTv, VTb, rsin, rcos);
  attn_k<<<dim3(16, 64), 256, 0, stream>>>(Qb, Kb, VTb, ctx);
  gemm_k<3><<<dim3(64, 8), 256, 0, stream>>>(ctx, WTo, d_out, rsin, rcos);
}